// Round 6
// baseline (3251.619 us; speedup 1.0000x reference)
//
#include <hip/hip_runtime.h>
#include <math.h>

#define THREADS 256
#define ROWS_PER_THREAD 2
// fp32-vs-fp64 p error is <~3e-6 worst case; 1e-4 margin is ~30x safety.
#define P_MARGIN 1e-4f

// Exact JAX threefry2x32 (20 rounds, key schedule every 4), key = (0, 42).
// Partitionable stream: bits[j] = o0 ^ o1 of threefry2x32(key, 0, j).
__device__ __forceinline__ void tf2x32(unsigned x0, unsigned x1,
                                       unsigned &o0, unsigned &o1) {
  const unsigned k0 = 0u;
  const unsigned k1 = 42u;
  const unsigned k2 = 0x1BD11BDAu ^ k0 ^ k1;
  x0 += k0; x1 += k1;
#define TF_R(r) { x0 += x1; x1 = (x1 << (r)) | (x1 >> (32 - (r))); x1 ^= x0; }
  TF_R(13) TF_R(15) TF_R(26) TF_R(6)
  x0 += k1; x1 += k2 + 1u;
  TF_R(17) TF_R(29) TF_R(16) TF_R(24)
  x0 += k2; x1 += k0 + 2u;
  TF_R(13) TF_R(15) TF_R(26) TF_R(6)
  x0 += k0; x1 += k1 + 3u;
  TF_R(17) TF_R(29) TF_R(16) TF_R(24)
  x0 += k1; x1 += k2 + 4u;
  TF_R(13) TF_R(15) TF_R(26) TF_R(6)
  x0 += k2; x1 += k0 + 5u;
#undef TF_R
  o0 = x0; o1 = x1;
}

// ---------------- Pass 1: fp32, LDS weights, 2 rows/thread ----------------
// Weights transposed to [n][k] (k padded to x4) in LDS; each ds_read_b128
// broadcast now feeds 8 FMAs (4 per row x 2 rows) -> LDS instr/row halved
// vs the 1-row version (which was LDS-issue bound at 143us).
__global__ __launch_bounds__(THREADS, 2)
void wtf_fast_kernel(const float* __restrict__ events,
                     const float* __restrict__ W1, const float* __restrict__ b1,
                     const float* __restrict__ g1, const float* __restrict__ be1,
                     const float* __restrict__ W2, const float* __restrict__ b2,
                     const float* __restrict__ g2, const float* __restrict__ be2,
                     const float* __restrict__ W3, const float* __restrict__ b3,
                     const float* __restrict__ g3, const float* __restrict__ be3,
                     const float* __restrict__ W4, const float* __restrict__ b4,
                     const float* __restrict__ W5, const float* __restrict__ b5,
                     float* __restrict__ out_chosen,
                     float* __restrict__ out_logp,
                     unsigned* __restrict__ fixlist,  // [0]=count, rows at [1+i]
                     unsigned fixcap,
                     int B) {
  __shared__ float4 sW1t[50 * 8];   // [n][k/4], k=32
  __shared__ float4 sW2t[30 * 13];  // k: 50 -> pad 52
  __shared__ float4 sW3t[20 * 8];   // k: 30 -> pad 32
  __shared__ float4 sW4t[15 * 5];   // k=20
  __shared__ float4 sW5t[8 * 4];    // k: 15 -> pad 16
  __shared__ float sb1[50], ss1[50], sbe1[50];
  __shared__ float sb2[30], ss2[30], sbe2[30];
  __shared__ float sb3[20], ss3[20], sbe3[20];
  __shared__ float sb4[15], sb5[8];

  const int t = threadIdx.x;
  {
    float* w = (float*)sW1t;
    for (int i = t; i < 1600; i += THREADS) { int n = i >> 5, k = i & 31; w[i] = W1[k * 50 + n]; }
    w = (float*)sW2t;
    for (int i = t; i < 1560; i += THREADS) { int n = i / 52, k = i - n * 52; w[i] = (k < 50) ? W2[k * 30 + n] : 0.f; }
    w = (float*)sW3t;
    for (int i = t; i < 640; i += THREADS)  { int n = i >> 5, k = i & 31; w[i] = (k < 30) ? W3[k * 20 + n] : 0.f; }
    w = (float*)sW4t;
    for (int i = t; i < 300; i += THREADS)  { int n = i / 20, k = i - n * 20; w[i] = W4[k * 15 + n]; }
    w = (float*)sW5t;
    for (int i = t; i < 128; i += THREADS)  { int n = i >> 4, k = i & 15; w[i] = (k < 15) ? W5[k * 8 + n] : 0.f; }
    const float rden = (float)(1.0 / sqrt(1.0 + 1e-5));
    if (t < 50) { sb1[t] = b1[t]; ss1[t] = g1[t] * rden; sbe1[t] = be1[t]; }
    if (t < 30) { sb2[t] = b2[t]; ss2[t] = g2[t] * rden; sbe2[t] = be2[t]; }
    if (t < 20) { sb3[t] = b3[t]; ss3[t] = g3[t] * rden; sbe3[t] = be3[t]; }
    if (t < 15) { sb4[t] = b4[t]; }
    if (t < 8)  { sb5[t] = b5[t]; }
  }
  __syncthreads();

  const int r0 = blockIdx.x * (THREADS * ROWS_PER_THREAD) + t;  // row 0
  const int r1 = r0 + THREADS;                                  // row 1
  if (r0 >= B) return;
  const bool has1 = (r1 < B);

  float x0[32], x1[32];
  {
    const float4* e0 = reinterpret_cast<const float4*>(events) + (size_t)r0 * 8;
    const float4* e1 = reinterpret_cast<const float4*>(events) + (size_t)(has1 ? r1 : r0) * 8;
#pragma unroll
    for (int q = 0; q < 8; ++q) {
      float4 v0 = e0[q], v1 = e1[q];
      x0[4 * q + 0] = v0.x; x0[4 * q + 1] = v0.y; x0[4 * q + 2] = v0.z; x0[4 * q + 3] = v0.w;
      x1[4 * q + 0] = v1.x; x1[4 * q + 1] = v1.y; x1[4 * q + 2] = v1.z; x1[4 * q + 3] = v1.w;
    }
  }

  // layer 1: 32 -> 50
  float a10[52], a11[52];
  a10[50] = a10[51] = a11[50] = a11[51] = 0.f;
#pragma unroll
  for (int n = 0; n < 50; ++n) {
    const float4* wr = &sW1t[n * 8];
    float d00 = 0.f, d01 = 0.f, d02 = 0.f, d03 = 0.f;
    float d10 = 0.f, d11 = 0.f, d12 = 0.f, d13 = 0.f;
#pragma unroll
    for (int q = 0; q < 8; ++q) {
      float4 wv = wr[q];
      d00 = fmaf(x0[4 * q + 0], wv.x, d00); d01 = fmaf(x0[4 * q + 1], wv.y, d01);
      d02 = fmaf(x0[4 * q + 2], wv.z, d02); d03 = fmaf(x0[4 * q + 3], wv.w, d03);
      d10 = fmaf(x1[4 * q + 0], wv.x, d10); d11 = fmaf(x1[4 * q + 1], wv.y, d11);
      d12 = fmaf(x1[4 * q + 2], wv.z, d12); d13 = fmaf(x1[4 * q + 3], wv.w, d13);
    }
    float s0 = (d00 + d01) + (d02 + d03) + sb1[n];
    float s1 = (d10 + d11) + (d12 + d13) + sb1[n];
    a10[n] = fmaxf(fmaf(s0, ss1[n], sbe1[n]), 0.f);
    a11[n] = fmaxf(fmaf(s1, ss1[n], sbe1[n]), 0.f);
  }

  // layer 2: 50 -> 30
  float a20[32], a21[32];
  a20[30] = a20[31] = a21[30] = a21[31] = 0.f;
#pragma unroll
  for (int n = 0; n < 30; ++n) {
    const float4* wr = &sW2t[n * 13];
    float d00 = 0.f, d01 = 0.f, d02 = 0.f, d03 = 0.f;
    float d10 = 0.f, d11 = 0.f, d12 = 0.f, d13 = 0.f;
#pragma unroll
    for (int q = 0; q < 13; ++q) {
      float4 wv = wr[q];
      d00 = fmaf(a10[4 * q + 0], wv.x, d00); d01 = fmaf(a10[4 * q + 1], wv.y, d01);
      d02 = fmaf(a10[4 * q + 2], wv.z, d02); d03 = fmaf(a10[4 * q + 3], wv.w, d03);
      d10 = fmaf(a11[4 * q + 0], wv.x, d10); d11 = fmaf(a11[4 * q + 1], wv.y, d11);
      d12 = fmaf(a11[4 * q + 2], wv.z, d12); d13 = fmaf(a11[4 * q + 3], wv.w, d13);
    }
    float s0 = (d00 + d01) + (d02 + d03) + sb2[n];
    float s1 = (d10 + d11) + (d12 + d13) + sb2[n];
    a20[n] = fmaxf(fmaf(s0, ss2[n], sbe2[n]), 0.f);
    a21[n] = fmaxf(fmaf(s1, ss2[n], sbe2[n]), 0.f);
  }

  // layer 3: 30 -> 20
  float a30[20], a31[20];
#pragma unroll
  for (int n = 0; n < 20; ++n) {
    const float4* wr = &sW3t[n * 8];
    float d00 = 0.f, d01 = 0.f, d02 = 0.f, d03 = 0.f;
    float d10 = 0.f, d11 = 0.f, d12 = 0.f, d13 = 0.f;
#pragma unroll
    for (int q = 0; q < 8; ++q) {
      float4 wv = wr[q];
      d00 = fmaf(a20[4 * q + 0], wv.x, d00); d01 = fmaf(a20[4 * q + 1], wv.y, d01);
      d02 = fmaf(a20[4 * q + 2], wv.z, d02); d03 = fmaf(a20[4 * q + 3], wv.w, d03);
      d10 = fmaf(a21[4 * q + 0], wv.x, d10); d11 = fmaf(a21[4 * q + 1], wv.y, d11);
      d12 = fmaf(a21[4 * q + 2], wv.z, d12); d13 = fmaf(a21[4 * q + 3], wv.w, d13);
    }
    float s0 = (d00 + d01) + (d02 + d03) + sb3[n];
    float s1 = (d10 + d11) + (d12 + d13) + sb3[n];
    a30[n] = fmaxf(fmaf(s0, ss3[n], sbe3[n]), 0.f);
    a31[n] = fmaxf(fmaf(s1, ss3[n], sbe3[n]), 0.f);
  }

  // layer 4: 20 -> 15 (no BN)
  float a40[16], a41[16];
  a40[15] = a41[15] = 0.f;
#pragma unroll
  for (int n = 0; n < 15; ++n) {
    const float4* wr = &sW4t[n * 5];
    float d00 = 0.f, d01 = 0.f, d02 = 0.f, d03 = 0.f;
    float d10 = 0.f, d11 = 0.f, d12 = 0.f, d13 = 0.f;
#pragma unroll
    for (int q = 0; q < 5; ++q) {
      float4 wv = wr[q];
      d00 = fmaf(a30[4 * q + 0], wv.x, d00); d01 = fmaf(a30[4 * q + 1], wv.y, d01);
      d02 = fmaf(a30[4 * q + 2], wv.z, d02); d03 = fmaf(a30[4 * q + 3], wv.w, d03);
      d10 = fmaf(a31[4 * q + 0], wv.x, d10); d11 = fmaf(a31[4 * q + 1], wv.y, d11);
      d12 = fmaf(a31[4 * q + 2], wv.z, d12); d13 = fmaf(a31[4 * q + 3], wv.w, d13);
    }
    a40[n] = fmaxf((d00 + d01) + (d02 + d03) + sb4[n], 0.f);
    a41[n] = fmaxf((d10 + d11) + (d12 + d13) + sb4[n], 0.f);
  }

  // layer 5: 15 -> 8, sigmoid
  float p0[8], p1[8];
#pragma unroll
  for (int n = 0; n < 8; ++n) {
    const float4* wr = &sW5t[n * 4];
    float d00 = 0.f, d01 = 0.f, d02 = 0.f, d03 = 0.f;
    float d10 = 0.f, d11 = 0.f, d12 = 0.f, d13 = 0.f;
#pragma unroll
    for (int q = 0; q < 4; ++q) {
      float4 wv = wr[q];
      d00 = fmaf(a40[4 * q + 0], wv.x, d00); d01 = fmaf(a40[4 * q + 1], wv.y, d01);
      d02 = fmaf(a40[4 * q + 2], wv.z, d02); d03 = fmaf(a40[4 * q + 3], wv.w, d03);
      d10 = fmaf(a41[4 * q + 0], wv.x, d10); d11 = fmaf(a41[4 * q + 1], wv.y, d11);
      d12 = fmaf(a41[4 * q + 2], wv.z, d12); d13 = fmaf(a41[4 * q + 3], wv.w, d13);
    }
    float s0 = (d00 + d01) + (d02 + d03) + sb5[n];
    float s1 = (d10 + d11) + (d12 + d13) + sb5[n];
    p0[n] = 1.f / (1.f + expf(-s0));
    p1[n] = 1.f / (1.f + expf(-s1));
  }

  // bernoulli(1-p) via partitionable threefry + margin flag, both rows
#pragma unroll
  for (int r = 0; r < 2; ++r) {
    const int b = r ? r1 : r0;
    if (r && !has1) break;
    const float* p = r ? p1 : p0;
    bool need = false;
    float prod = 1.f;
    float ch[8];
#pragma unroll
    for (int w = 0; w < 8; ++w) {
      unsigned j = 8u * (unsigned)b + (unsigned)w, o0, o1;
      tf2x32(0u, j, o0, o1);
      unsigned bits = o0 ^ o1;
      float u = __uint_as_float(0x3F800000u | (bits >> 9)) - 1.f;
      float thr = 1.f - p[w];
      bool choice = u < thr;
      need = need || (fabsf(u - thr) < P_MARGIN);
      ch[w] = choice ? 0.f : 1.f;
      prod *= choice ? thr : p[w];
    }
    if (need) {
      unsigned i = atomicAdd(&fixlist[0], 1u);
      if (i < fixcap) fixlist[1 + i] = (unsigned)b;
    }
    float4* oc = reinterpret_cast<float4*>(out_chosen) + (size_t)b * 2;
    oc[0] = make_float4(ch[0], ch[1], ch[2], ch[3]);
    oc[1] = make_float4(ch[4], ch[5], ch[6], ch[7]);
    out_logp[b] = logf(prod);
  }
}

// ---------------- Pass 2: wave-cooperative fp64 repair, unrolled ----------
// One 64-lane wave per flagged row; lane n computes output neuron n. k-loops
// fully unrolled so all coalesced weight loads issue before the FMA chain
// (R5's one-thread-per-row variant spilled at 256 VGPR -> 1810us; this shape
// is ~10 regs/lane hot state, no spills).
__global__ __launch_bounds__(64, 4)
void wtf_fix_kernel(const float* __restrict__ events,
                    const float* __restrict__ W1, const float* __restrict__ b1,
                    const float* __restrict__ g1, const float* __restrict__ be1,
                    const float* __restrict__ W2, const float* __restrict__ b2,
                    const float* __restrict__ g2, const float* __restrict__ be2,
                    const float* __restrict__ W3, const float* __restrict__ b3,
                    const float* __restrict__ g3, const float* __restrict__ be3,
                    const float* __restrict__ W4, const float* __restrict__ b4,
                    const float* __restrict__ W5, const float* __restrict__ b5,
                    float* __restrict__ out_chosen,
                    float* __restrict__ out_logp,
                    const unsigned* __restrict__ fixlist,
                    unsigned fixcap,
                    int B) {
  const unsigned raw = fixlist[0];
  const unsigned cnt = raw < fixcap ? raw : fixcap;
  if (blockIdx.x >= cnt) return;

  __shared__ double sA[64];
  __shared__ double sB[64];
  __shared__ double sF[8];

  const int t = threadIdx.x;
  const double denom = sqrt(1.0 + 1e-5);

  for (unsigned idx = blockIdx.x; idx < cnt; idx += gridDim.x) {
    const int b = (int)fixlist[1 + idx];

    if (t < 32) sA[t] = (double)events[(size_t)b * 32 + t];
    __syncthreads();

    // layer 1: 32 -> 50 (+BN+ReLU); lane t = neuron t, W1[k*50+t] coalesced
    double v = 0.0;
    if (t < 50) {
#pragma unroll
      for (int k = 0; k < 32; ++k) v = fma(sA[k], (double)W1[k * 50 + t], v);
      v += (double)b1[t];
      v = v * ((double)g1[t] / denom) + (double)be1[t];
      v = v > 0.0 ? v : 0.0;
    }
    __syncthreads();
    if (t < 50) sB[t] = v;
    __syncthreads();

    // layer 2: 50 -> 30
    v = 0.0;
    if (t < 30) {
#pragma unroll
      for (int k = 0; k < 50; ++k) v = fma(sB[k], (double)W2[k * 30 + t], v);
      v += (double)b2[t];
      v = v * ((double)g2[t] / denom) + (double)be2[t];
      v = v > 0.0 ? v : 0.0;
    }
    __syncthreads();
    if (t < 30) sA[t] = v;
    __syncthreads();

    // layer 3: 30 -> 20
    v = 0.0;
    if (t < 20) {
#pragma unroll
      for (int k = 0; k < 30; ++k) v = fma(sA[k], (double)W3[k * 20 + t], v);
      v += (double)b3[t];
      v = v * ((double)g3[t] / denom) + (double)be3[t];
      v = v > 0.0 ? v : 0.0;
    }
    __syncthreads();
    if (t < 20) sB[t] = v;
    __syncthreads();

    // layer 4: 20 -> 15 (no BN)
    v = 0.0;
    if (t < 15) {
#pragma unroll
      for (int k = 0; k < 20; ++k) v = fma(sB[k], (double)W4[k * 15 + t], v);
      v += (double)b4[t];
      v = v > 0.0 ? v : 0.0;
    }
    __syncthreads();
    if (t < 15) sA[t] = v;
    __syncthreads();

    // layer 5: 15 -> 8, sigmoid; then bernoulli + flipped prob
    if (t < 8) {
      v = 0.0;
#pragma unroll
      for (int k = 0; k < 15; ++k) v = fma(sA[k], (double)W5[k * 8 + t], v);
      v += (double)b5[t];
      double p = 1.0 / (1.0 + exp(-v));
      unsigned j = 8u * (unsigned)b + (unsigned)t, o0, o1;
      tf2x32(0u, j, o0, o1);
      unsigned bits = o0 ^ o1;
      float u = __uint_as_float(0x3F800000u | (bits >> 9)) - 1.f;
      double thr = 1.0 - p;
      bool choice = ((double)u < thr);
      out_chosen[(size_t)b * 8 + t] = choice ? 0.f : 1.f;
      sF[t] = choice ? thr : p;
    }
    __syncthreads();
    if (t == 0) {
      double prod = 1.0;
      for (int w = 0; w < 8; ++w) prod *= sF[w];
      out_logp[b] = (float)log(prod);
    }
    __syncthreads();
  }
}

extern "C" void kernel_launch(void* const* d_in, const int* in_sizes, int n_in,
                              void* d_out, int out_size, void* d_ws, size_t ws_size,
                              hipStream_t stream) {
  const float* events = (const float*)d_in[0];
  const float* W1  = (const float*)d_in[1];
  const float* b1  = (const float*)d_in[2];
  const float* g1  = (const float*)d_in[3];
  const float* be1 = (const float*)d_in[4];
  const float* W2  = (const float*)d_in[5];
  const float* b2  = (const float*)d_in[6];
  const float* g2  = (const float*)d_in[7];
  const float* be2 = (const float*)d_in[8];
  const float* W3  = (const float*)d_in[9];
  const float* b3  = (const float*)d_in[10];
  const float* g3  = (const float*)d_in[11];
  const float* be3 = (const float*)d_in[12];
  const float* W4  = (const float*)d_in[13];
  const float* b4  = (const float*)d_in[14];
  const float* W5  = (const float*)d_in[15];
  const float* b5  = (const float*)d_in[16];

  const int B = in_sizes[0] / 32;  // 524288
  float* out = (float*)d_out;
  float* out_chosen = out;                   // (B, 8)
  float* out_logp   = out + (size_t)B * 8;   // (B,)
  unsigned* fixlist = (unsigned*)d_ws;       // [0]=count, rows at [1+i]
  unsigned fixcap = (unsigned)(ws_size / sizeof(unsigned) - 1);
  if (fixcap > (unsigned)B) fixcap = (unsigned)B;

  hipMemsetAsync(d_ws, 0, sizeof(unsigned), stream);  // zero the counter

  const int rows_per_block = THREADS * ROWS_PER_THREAD;
  const int blocks = (B + rows_per_block - 1) / rows_per_block;
  hipLaunchKernelGGL(wtf_fast_kernel, dim3(blocks), dim3(THREADS), 0, stream,
                     events, W1, b1, g1, be1, W2, b2, g2, be2,
                     W3, b3, g3, be3, W4, b4, W5, b5,
                     out_chosen, out_logp, fixlist, fixcap, B);
  hipLaunchKernelGGL(wtf_fix_kernel, dim3(1024), dim3(64), 0, stream,
                     events, W1, b1, g1, be1, W2, b2, g2, be2,
                     W3, b3, g3, be3, W4, b4, W5, b5,
                     out_chosen, out_logp, fixlist, fixcap, B);
}

// Round 7
// 2957.893 us; speedup vs baseline: 1.0993x; 1.0993x over previous
//
#include <hip/hip_runtime.h>
#include <math.h>

#define THREADS 256
#define ROWS_PER_BLOCK (THREADS * 2)
// fp32-vs-fp64 p error is <~3e-6 worst case; 1e-4 margin is ~30x safety.
#define P_MARGIN 1e-4f

// Exact JAX threefry2x32 (20 rounds, key schedule every 4), key = (0, 42).
// Partitionable stream: bits[j] = o0 ^ o1 of threefry2x32(key, 0, j).
__device__ __forceinline__ void tf2x32(unsigned x0, unsigned x1,
                                       unsigned &o0, unsigned &o1) {
  const unsigned k0 = 0u;
  const unsigned k1 = 42u;
  const unsigned k2 = 0x1BD11BDAu ^ k0 ^ k1;
  x0 += k0; x1 += k1;
#define TF_R(r) { x0 += x1; x1 = (x1 << (r)) | (x1 >> (32 - (r))); x1 ^= x0; }
  TF_R(13) TF_R(15) TF_R(26) TF_R(6)
  x0 += k1; x1 += k2 + 1u;
  TF_R(17) TF_R(29) TF_R(16) TF_R(24)
  x0 += k2; x1 += k0 + 2u;
  TF_R(13) TF_R(15) TF_R(26) TF_R(6)
  x0 += k0; x1 += k1 + 3u;
  TF_R(17) TF_R(29) TF_R(16) TF_R(24)
  x0 += k1; x1 += k2 + 4u;
  TF_R(13) TF_R(15) TF_R(26) TF_R(6)
  x0 += k2; x1 += k0 + 5u;
#undef TF_R
  o0 = x0; o1 = x1;
}

// ---------------- Pass 1: fp32, LDS weights, 2 rows/thread, FUSED --------
// Layer boundaries fused at neuron granularity: as soon as a layer-l neuron
// h is ready, accumulate h * W_{l+1}[k][:] into next-layer accumulators and
// drop h. Peak live set ~150 floats (R6's unfused 2-row held ~190 and the
// allocator spilled 8.8GB to scratch at VGPR=128). Next-layer weights are
// stored k-major (n contiguous, padded to x4) so fused reads stay broadcast
// ds_read_b128. Each b128 now feeds 8 FMAs (4 lanes x 2 rows) -> LDS
// instr/row halved vs R4's 143us kernel.
__global__ __launch_bounds__(THREADS)
void wtf_fast_kernel(const float* __restrict__ events,
                     const float* __restrict__ W1, const float* __restrict__ b1,
                     const float* __restrict__ g1, const float* __restrict__ be1,
                     const float* __restrict__ W2, const float* __restrict__ b2,
                     const float* __restrict__ g2, const float* __restrict__ be2,
                     const float* __restrict__ W3, const float* __restrict__ b3,
                     const float* __restrict__ g3, const float* __restrict__ be3,
                     const float* __restrict__ W4, const float* __restrict__ b4,
                     const float* __restrict__ W5, const float* __restrict__ b5,
                     float* __restrict__ out_chosen,
                     float* __restrict__ out_logp,
                     unsigned* __restrict__ fixlist,  // [0]=count, rows at [1+i]
                     unsigned fixcap,
                     int B) {
  __shared__ float4 sW1t[50 * 8];  // [n][k/4], k=32       (n-major, dot)
  __shared__ float4 sW2k[50 * 8];  // [k][n/4], n 30->32   (k-major, fused acc)
  __shared__ float4 sW3k[30 * 5];  // [k][n/4], n=20
  __shared__ float4 sW4k[20 * 4];  // [k][n/4], n 15->16
  __shared__ float4 sW5k[15 * 2];  // [k][n/4], n=8
  __shared__ float sb1[50], ss1[50], sbe1[50];
  __shared__ float sb2[30], ss2[30], sbe2[30];
  __shared__ float sb3[20], ss3[20], sbe3[20];
  __shared__ float sb4[15], sb5[8];

  const int t = threadIdx.x;
  {
    float* w = (float*)sW1t;
    for (int i = t; i < 1600; i += THREADS) { int n = i >> 5, k = i & 31; w[i] = W1[k * 50 + n]; }
    w = (float*)sW2k;
    for (int i = t; i < 1600; i += THREADS) { int k = i >> 5, n = i & 31; w[i] = (n < 30) ? W2[k * 30 + n] : 0.f; }
    w = (float*)sW3k;
    for (int i = t; i < 600; i += THREADS)  { int k = i / 20, n = i - k * 20; w[i] = W3[k * 20 + n]; }
    w = (float*)sW4k;
    for (int i = t; i < 320; i += THREADS)  { int k = i >> 4, n = i & 15; w[i] = (n < 15) ? W4[k * 15 + n] : 0.f; }
    w = (float*)sW5k;
    for (int i = t; i < 120; i += THREADS)  { int k = i >> 3, n = i & 7; w[i] = W5[k * 8 + n]; }
    const float rden = (float)(1.0 / sqrt(1.0 + 1e-5));
    if (t < 50) { sb1[t] = b1[t]; ss1[t] = g1[t] * rden; sbe1[t] = be1[t]; }
    if (t < 30) { sb2[t] = b2[t]; ss2[t] = g2[t] * rden; sbe2[t] = be2[t]; }
    if (t < 20) { sb3[t] = b3[t]; ss3[t] = g3[t] * rden; sbe3[t] = be3[t]; }
    if (t < 15) { sb4[t] = b4[t]; }
    if (t < 8)  { sb5[t] = b5[t]; }
  }
  __syncthreads();

  const int r0 = blockIdx.x * ROWS_PER_BLOCK + t;  // row 0
  const int r1 = r0 + THREADS;                     // row 1
  if (r0 >= B) return;
  const bool has1 = (r1 < B);

  float x0[32], x1[32];
  {
    const float4* e0 = reinterpret_cast<const float4*>(events) + (size_t)r0 * 8;
    const float4* e1 = reinterpret_cast<const float4*>(events) + (size_t)(has1 ? r1 : r0) * 8;
#pragma unroll
    for (int q = 0; q < 8; ++q) {
      float4 v0 = e0[q], v1 = e1[q];
      x0[4 * q + 0] = v0.x; x0[4 * q + 1] = v0.y; x0[4 * q + 2] = v0.z; x0[4 * q + 3] = v0.w;
      x1[4 * q + 0] = v1.x; x1[4 * q + 1] = v1.y; x1[4 * q + 2] = v1.z; x1[4 * q + 3] = v1.w;
    }
  }

  // ---- fused layer1 (32->50, BN+ReLU) -> layer2 accumulation ----
  float A0[32], A1[32];  // layer-2 accumulators (n padded 30->32)
#pragma unroll
  for (int n = 0; n < 32; ++n) {
    float bi = (n < 30) ? sb2[n] : 0.f;
    A0[n] = bi; A1[n] = bi;
  }
#pragma unroll
  for (int n = 0; n < 50; ++n) {
    const float4* wr = &sW1t[n * 8];
    float d00 = 0.f, d01 = 0.f, d02 = 0.f, d03 = 0.f;
    float d10 = 0.f, d11 = 0.f, d12 = 0.f, d13 = 0.f;
#pragma unroll
    for (int q = 0; q < 8; ++q) {
      float4 wv = wr[q];
      d00 = fmaf(x0[4 * q + 0], wv.x, d00); d01 = fmaf(x0[4 * q + 1], wv.y, d01);
      d02 = fmaf(x0[4 * q + 2], wv.z, d02); d03 = fmaf(x0[4 * q + 3], wv.w, d03);
      d10 = fmaf(x1[4 * q + 0], wv.x, d10); d11 = fmaf(x1[4 * q + 1], wv.y, d11);
      d12 = fmaf(x1[4 * q + 2], wv.z, d12); d13 = fmaf(x1[4 * q + 3], wv.w, d13);
    }
    float h0 = fmaxf(fmaf((d00 + d01) + (d02 + d03) + sb1[n], ss1[n], sbe1[n]), 0.f);
    float h1 = fmaxf(fmaf((d10 + d11) + (d12 + d13) + sb1[n], ss1[n], sbe1[n]), 0.f);
    const float4* wk = &sW2k[n * 8];
#pragma unroll
    for (int j = 0; j < 8; ++j) {
      float4 wv = wk[j];
      A0[4 * j + 0] = fmaf(h0, wv.x, A0[4 * j + 0]); A0[4 * j + 1] = fmaf(h0, wv.y, A0[4 * j + 1]);
      A0[4 * j + 2] = fmaf(h0, wv.z, A0[4 * j + 2]); A0[4 * j + 3] = fmaf(h0, wv.w, A0[4 * j + 3]);
      A1[4 * j + 0] = fmaf(h1, wv.x, A1[4 * j + 0]); A1[4 * j + 1] = fmaf(h1, wv.y, A1[4 * j + 1]);
      A1[4 * j + 2] = fmaf(h1, wv.z, A1[4 * j + 2]); A1[4 * j + 3] = fmaf(h1, wv.w, A1[4 * j + 3]);
    }
  }
  // layer-2 BN + ReLU in place
#pragma unroll
  for (int n = 0; n < 30; ++n) {
    A0[n] = fmaxf(fmaf(A0[n], ss2[n], sbe2[n]), 0.f);
    A1[n] = fmaxf(fmaf(A1[n], ss2[n], sbe2[n]), 0.f);
  }

  // ---- fused layer3 accumulation (30->20, BN+ReLU) ----
  float C0[20], C1[20];
#pragma unroll
  for (int n = 0; n < 20; ++n) { C0[n] = sb3[n]; C1[n] = sb3[n]; }
#pragma unroll
  for (int k = 0; k < 30; ++k) {
    const float h0 = A0[k], h1 = A1[k];
    const float4* wk = &sW3k[k * 5];
#pragma unroll
    for (int j = 0; j < 5; ++j) {
      float4 wv = wk[j];
      C0[4 * j + 0] = fmaf(h0, wv.x, C0[4 * j + 0]); C0[4 * j + 1] = fmaf(h0, wv.y, C0[4 * j + 1]);
      C0[4 * j + 2] = fmaf(h0, wv.z, C0[4 * j + 2]); C0[4 * j + 3] = fmaf(h0, wv.w, C0[4 * j + 3]);
      C1[4 * j + 0] = fmaf(h1, wv.x, C1[4 * j + 0]); C1[4 * j + 1] = fmaf(h1, wv.y, C1[4 * j + 1]);
      C1[4 * j + 2] = fmaf(h1, wv.z, C1[4 * j + 2]); C1[4 * j + 3] = fmaf(h1, wv.w, C1[4 * j + 3]);
    }
  }
#pragma unroll
  for (int n = 0; n < 20; ++n) {
    C0[n] = fmaxf(fmaf(C0[n], ss3[n], sbe3[n]), 0.f);
    C1[n] = fmaxf(fmaf(C1[n], ss3[n], sbe3[n]), 0.f);
  }

  // ---- fused layer4 accumulation (20->15, ReLU, no BN) ----
  float D0[16], D1[16];
#pragma unroll
  for (int n = 0; n < 16; ++n) {
    float bi = (n < 15) ? sb4[n] : 0.f;
    D0[n] = bi; D1[n] = bi;
  }
#pragma unroll
  for (int k = 0; k < 20; ++k) {
    const float h0 = C0[k], h1 = C1[k];
    const float4* wk = &sW4k[k * 4];
#pragma unroll
    for (int j = 0; j < 4; ++j) {
      float4 wv = wk[j];
      D0[4 * j + 0] = fmaf(h0, wv.x, D0[4 * j + 0]); D0[4 * j + 1] = fmaf(h0, wv.y, D0[4 * j + 1]);
      D0[4 * j + 2] = fmaf(h0, wv.z, D0[4 * j + 2]); D0[4 * j + 3] = fmaf(h0, wv.w, D0[4 * j + 3]);
      D1[4 * j + 0] = fmaf(h1, wv.x, D1[4 * j + 0]); D1[4 * j + 1] = fmaf(h1, wv.y, D1[4 * j + 1]);
      D1[4 * j + 2] = fmaf(h1, wv.z, D1[4 * j + 2]); D1[4 * j + 3] = fmaf(h1, wv.w, D1[4 * j + 3]);
    }
  }
#pragma unroll
  for (int n = 0; n < 15; ++n) { D0[n] = fmaxf(D0[n], 0.f); D1[n] = fmaxf(D1[n], 0.f); }

  // ---- fused layer5 accumulation (15->8) + sigmoid ----
  float p0[8], p1[8];
#pragma unroll
  for (int n = 0; n < 8; ++n) { p0[n] = sb5[n]; p1[n] = sb5[n]; }
#pragma unroll
  for (int k = 0; k < 15; ++k) {
    const float h0 = D0[k], h1 = D1[k];
    const float4* wk = &sW5k[k * 2];
#pragma unroll
    for (int j = 0; j < 2; ++j) {
      float4 wv = wk[j];
      p0[4 * j + 0] = fmaf(h0, wv.x, p0[4 * j + 0]); p0[4 * j + 1] = fmaf(h0, wv.y, p0[4 * j + 1]);
      p0[4 * j + 2] = fmaf(h0, wv.z, p0[4 * j + 2]); p0[4 * j + 3] = fmaf(h0, wv.w, p0[4 * j + 3]);
      p1[4 * j + 0] = fmaf(h1, wv.x, p1[4 * j + 0]); p1[4 * j + 1] = fmaf(h1, wv.y, p1[4 * j + 1]);
      p1[4 * j + 2] = fmaf(h1, wv.z, p1[4 * j + 2]); p1[4 * j + 3] = fmaf(h1, wv.w, p1[4 * j + 3]);
    }
  }
#pragma unroll
  for (int n = 0; n < 8; ++n) {
    p0[n] = 1.f / (1.f + expf(-p0[n]));
    p1[n] = 1.f / (1.f + expf(-p1[n]));
  }

  // bernoulli(1-p) via partitionable threefry + margin flag, both rows
#pragma unroll
  for (int r = 0; r < 2; ++r) {
    if (r && !has1) break;
    const int b = r ? r1 : r0;
    const float* p = r ? p1 : p0;
    bool need = false;
    float prod = 1.f;
    float ch[8];
#pragma unroll
    for (int w = 0; w < 8; ++w) {
      unsigned j = 8u * (unsigned)b + (unsigned)w, o0, o1;
      tf2x32(0u, j, o0, o1);
      unsigned bits = o0 ^ o1;
      float u = __uint_as_float(0x3F800000u | (bits >> 9)) - 1.f;
      float thr = 1.f - p[w];
      bool choice = u < thr;
      need = need || (fabsf(u - thr) < P_MARGIN);
      ch[w] = choice ? 0.f : 1.f;
      prod *= choice ? thr : p[w];
    }
    if (need) {
      unsigned i = atomicAdd(&fixlist[0], 1u);
      if (i < fixcap) fixlist[1 + i] = (unsigned)b;
    }
    float4* oc = reinterpret_cast<float4*>(out_chosen) + (size_t)b * 2;
    oc[0] = make_float4(ch[0], ch[1], ch[2], ch[3]);
    oc[1] = make_float4(ch[4], ch[5], ch[6], ch[7]);
    out_logp[b] = logf(prod);
  }
}

// ---------------- Pass 2: wave-cooperative fp64 repair, unrolled ----------
// One 64-lane wave per flagged row; lane n computes output neuron n. ~10
// regs/lane hot state, no spills (R5's thread-per-row spilled at 256 VGPR).
__global__ __launch_bounds__(64, 4)
void wtf_fix_kernel(const float* __restrict__ events,
                    const float* __restrict__ W1, const float* __restrict__ b1,
                    const float* __restrict__ g1, const float* __restrict__ be1,
                    const float* __restrict__ W2, const float* __restrict__ b2,
                    const float* __restrict__ g2, const float* __restrict__ be2,
                    const float* __restrict__ W3, const float* __restrict__ b3,
                    const float* __restrict__ g3, const float* __restrict__ be3,
                    const float* __restrict__ W4, const float* __restrict__ b4,
                    const float* __restrict__ W5, const float* __restrict__ b5,
                    float* __restrict__ out_chosen,
                    float* __restrict__ out_logp,
                    const unsigned* __restrict__ fixlist,
                    unsigned fixcap,
                    int B) {
  const unsigned raw = fixlist[0];
  const unsigned cnt = raw < fixcap ? raw : fixcap;
  if (blockIdx.x >= cnt) return;

  __shared__ double sA[64];
  __shared__ double sB[64];
  __shared__ double sF[8];

  const int t = threadIdx.x;
  const double denom = sqrt(1.0 + 1e-5);

  for (unsigned idx = blockIdx.x; idx < cnt; idx += gridDim.x) {
    const int b = (int)fixlist[1 + idx];

    if (t < 32) sA[t] = (double)events[(size_t)b * 32 + t];
    __syncthreads();

    double v = 0.0;
    if (t < 50) {
#pragma unroll
      for (int k = 0; k < 32; ++k) v = fma(sA[k], (double)W1[k * 50 + t], v);
      v += (double)b1[t];
      v = v * ((double)g1[t] / denom) + (double)be1[t];
      v = v > 0.0 ? v : 0.0;
    }
    __syncthreads();
    if (t < 50) sB[t] = v;
    __syncthreads();

    v = 0.0;
    if (t < 30) {
#pragma unroll
      for (int k = 0; k < 50; ++k) v = fma(sB[k], (double)W2[k * 30 + t], v);
      v += (double)b2[t];
      v = v * ((double)g2[t] / denom) + (double)be2[t];
      v = v > 0.0 ? v : 0.0;
    }
    __syncthreads();
    if (t < 30) sA[t] = v;
    __syncthreads();

    v = 0.0;
    if (t < 20) {
#pragma unroll
      for (int k = 0; k < 30; ++k) v = fma(sA[k], (double)W3[k * 20 + t], v);
      v += (double)b3[t];
      v = v * ((double)g3[t] / denom) + (double)be3[t];
      v = v > 0.0 ? v : 0.0;
    }
    __syncthreads();
    if (t < 20) sB[t] = v;
    __syncthreads();

    v = 0.0;
    if (t < 15) {
#pragma unroll
      for (int k = 0; k < 20; ++k) v = fma(sB[k], (double)W4[k * 15 + t], v);
      v += (double)b4[t];
      v = v > 0.0 ? v : 0.0;
    }
    __syncthreads();
    if (t < 15) sA[t] = v;
    __syncthreads();

    if (t < 8) {
      v = 0.0;
#pragma unroll
      for (int k = 0; k < 15; ++k) v = fma(sA[k], (double)W5[k * 8 + t], v);
      v += (double)b5[t];
      double p = 1.0 / (1.0 + exp(-v));
      unsigned j = 8u * (unsigned)b + (unsigned)t, o0, o1;
      tf2x32(0u, j, o0, o1);
      unsigned bits = o0 ^ o1;
      float u = __uint_as_float(0x3F800000u | (bits >> 9)) - 1.f;
      double thr = 1.0 - p;
      bool choice = ((double)u < thr);
      out_chosen[(size_t)b * 8 + t] = choice ? 0.f : 1.f;
      sF[t] = choice ? thr : p;
    }
    __syncthreads();
    if (t == 0) {
      double prod = 1.0;
      for (int w = 0; w < 8; ++w) prod *= sF[w];
      out_logp[b] = (float)log(prod);
    }
    __syncthreads();
  }
}

extern "C" void kernel_launch(void* const* d_in, const int* in_sizes, int n_in,
                              void* d_out, int out_size, void* d_ws, size_t ws_size,
                              hipStream_t stream) {
  const float* events = (const float*)d_in[0];
  const float* W1  = (const float*)d_in[1];
  const float* b1  = (const float*)d_in[2];
  const float* g1  = (const float*)d_in[3];
  const float* be1 = (const float*)d_in[4];
  const float* W2  = (const float*)d_in[5];
  const float* b2  = (const float*)d_in[6];
  const float* g2  = (const float*)d_in[7];
  const float* be2 = (const float*)d_in[8];
  const float* W3  = (const float*)d_in[9];
  const float* b3  = (const float*)d_in[10];
  const float* g3  = (const float*)d_in[11];
  const float* be3 = (const float*)d_in[12];
  const float* W4  = (const float*)d_in[13];
  const float* b4  = (const float*)d_in[14];
  const float* W5  = (const float*)d_in[15];
  const float* b5  = (const float*)d_in[16];

  const int B = in_sizes[0] / 32;  // 524288
  float* out = (float*)d_out;
  float* out_chosen = out;                   // (B, 8)
  float* out_logp   = out + (size_t)B * 8;   // (B,)
  unsigned* fixlist = (unsigned*)d_ws;       // [0]=count, rows at [1+i]
  unsigned fixcap = (unsigned)(ws_size / sizeof(unsigned) - 1);
  if (fixcap > (unsigned)B) fixcap = (unsigned)B;

  hipMemsetAsync(d_ws, 0, sizeof(unsigned), stream);  // zero the counter

  const int blocks = (B + ROWS_PER_BLOCK - 1) / ROWS_PER_BLOCK;
  hipLaunchKernelGGL(wtf_fast_kernel, dim3(blocks), dim3(THREADS), 0, stream,
                     events, W1, b1, g1, be1, W2, b2, g2, be2,
                     W3, b3, g3, be3, W4, b4, W5, b5,
                     out_chosen, out_logp, fixlist, fixcap, B);
  hipLaunchKernelGGL(wtf_fix_kernel, dim3(1024), dim3(64), 0, stream,
                     events, W1, b1, g1, be1, W2, b2, g2, be2,
                     W3, b3, g3, be3, W4, b4, W5, b5,
                     out_chosen, out_logp, fixlist, fixcap, B);
}

// Round 8
// 237.925 us; speedup vs baseline: 13.6666x; 12.4321x over previous
//
#include <hip/hip_runtime.h>
#include <math.h>

#define THREADS 256
// fp32-vs-fp64 p error is <~3e-6 worst case; 1e-4 margin is ~30x safety.
#define P_MARGIN 1e-4f

// Exact JAX threefry2x32 (20 rounds, key schedule every 4), key = (0, 42).
// Partitionable stream: bits[j] = o0 ^ o1 of threefry2x32(key, 0, j).
__device__ __forceinline__ void tf2x32(unsigned x0, unsigned x1,
                                       unsigned &o0, unsigned &o1) {
  const unsigned k0 = 0u;
  const unsigned k1 = 42u;
  const unsigned k2 = 0x1BD11BDAu ^ k0 ^ k1;
  x0 += k0; x1 += k1;
#define TF_R(r) { x0 += x1; x1 = (x1 << (r)) | (x1 >> (32 - (r))); x1 ^= x0; }
  TF_R(13) TF_R(15) TF_R(26) TF_R(6)
  x0 += k1; x1 += k2 + 1u;
  TF_R(17) TF_R(29) TF_R(16) TF_R(24)
  x0 += k2; x1 += k0 + 2u;
  TF_R(13) TF_R(15) TF_R(26) TF_R(6)
  x0 += k0; x1 += k1 + 3u;
  TF_R(17) TF_R(29) TF_R(16) TF_R(24)
  x0 += k1; x1 += k2 + 4u;
  TF_R(13) TF_R(15) TF_R(26) TF_R(6)
  x0 += k2; x1 += k0 + 5u;
#undef TF_R
  o0 = x0; o1 = x1;
}

// ---------------- Pass 1: fp32, scalar-path weights (R5 shape) -----------
// All weight/bias indices are compile-time constants off uniform kernel-arg
// pointers -> s_load through the scalar cache; one fetch per WAVE serves all
// 64 rows. No LDS. k-outer/n-inner keeps weight reads contiguous/mergeable.
// (R5 inference: this kernel ran ~60-95us; it was masked by a 1810us repair
// kernel. R6/R7 2-row LDS variants spilled multi-GB scratch - dead end.)
__global__ __launch_bounds__(THREADS, 4)
void wtf_fast_kernel(const float* __restrict__ events,
                     const float* __restrict__ W1, const float* __restrict__ b1,
                     const float* __restrict__ g1, const float* __restrict__ be1,
                     const float* __restrict__ W2, const float* __restrict__ b2,
                     const float* __restrict__ g2, const float* __restrict__ be2,
                     const float* __restrict__ W3, const float* __restrict__ b3,
                     const float* __restrict__ g3, const float* __restrict__ be3,
                     const float* __restrict__ W4, const float* __restrict__ b4,
                     const float* __restrict__ W5, const float* __restrict__ b5,
                     float* __restrict__ out_chosen,
                     float* __restrict__ out_logp,
                     unsigned* __restrict__ fixlist,  // [0]=count, rows at [1+i]
                     unsigned fixcap,
                     int B) {
  const int b = blockIdx.x * THREADS + threadIdx.x;
  if (b >= B) return;

  const float rden = (float)(1.0 / sqrt(1.0 + 1e-5));

  float x[32];
  const float4* ev4 = reinterpret_cast<const float4*>(events) + (size_t)b * 8;
#pragma unroll
  for (int q = 0; q < 8; ++q) {
    float4 v = ev4[q];
    x[4 * q + 0] = v.x; x[4 * q + 1] = v.y; x[4 * q + 2] = v.z; x[4 * q + 3] = v.w;
  }

  // layer 1: 32 -> 50, BN(eval) + ReLU
  float a1[50];
#pragma unroll
  for (int n = 0; n < 50; ++n) a1[n] = b1[n];
#pragma unroll
  for (int k = 0; k < 32; ++k) {
    const float xk = x[k];
#pragma unroll
    for (int n = 0; n < 50; ++n) a1[n] = fmaf(xk, W1[k * 50 + n], a1[n]);
  }
#pragma unroll
  for (int n = 0; n < 50; ++n) {
    float s = fmaf(a1[n], g1[n] * rden, be1[n]);
    a1[n] = fmaxf(s, 0.f);
  }

  // layer 2: 50 -> 30, BN(eval) + ReLU
  float a2[30];
#pragma unroll
  for (int n = 0; n < 30; ++n) a2[n] = b2[n];
#pragma unroll
  for (int k = 0; k < 50; ++k) {
    const float ak = a1[k];
#pragma unroll
    for (int n = 0; n < 30; ++n) a2[n] = fmaf(ak, W2[k * 30 + n], a2[n]);
  }
#pragma unroll
  for (int n = 0; n < 30; ++n) {
    float s = fmaf(a2[n], g2[n] * rden, be2[n]);
    a2[n] = fmaxf(s, 0.f);
  }

  // layer 3: 30 -> 20, BN(eval) + ReLU
  float a3[20];
#pragma unroll
  for (int n = 0; n < 20; ++n) a3[n] = b3[n];
#pragma unroll
  for (int k = 0; k < 30; ++k) {
    const float ak = a2[k];
#pragma unroll
    for (int n = 0; n < 20; ++n) a3[n] = fmaf(ak, W3[k * 20 + n], a3[n]);
  }
#pragma unroll
  for (int n = 0; n < 20; ++n) {
    float s = fmaf(a3[n], g3[n] * rden, be3[n]);
    a3[n] = fmaxf(s, 0.f);
  }

  // layer 4: 20 -> 15, ReLU (no BN)
  float a4[15];
#pragma unroll
  for (int n = 0; n < 15; ++n) a4[n] = b4[n];
#pragma unroll
  for (int k = 0; k < 20; ++k) {
    const float ak = a3[k];
#pragma unroll
    for (int n = 0; n < 15; ++n) a4[n] = fmaf(ak, W4[k * 15 + n], a4[n]);
  }
#pragma unroll
  for (int n = 0; n < 15; ++n) a4[n] = fmaxf(a4[n], 0.f);

  // layer 5: 15 -> 8, sigmoid
  float p[8];
#pragma unroll
  for (int n = 0; n < 8; ++n) p[n] = b5[n];
#pragma unroll
  for (int k = 0; k < 15; ++k) {
    const float ak = a4[k];
#pragma unroll
    for (int n = 0; n < 8; ++n) p[n] = fmaf(ak, W5[k * 8 + n], p[n]);
  }
#pragma unroll
  for (int n = 0; n < 8; ++n) p[n] = 1.f / (1.f + expf(-p[n]));

  // bernoulli(1-p) via partitionable threefry + margin flag
  bool need = false;
  float prod = 1.f;
  float ch[8];
#pragma unroll
  for (int w = 0; w < 8; ++w) {
    unsigned j = 8u * (unsigned)b + (unsigned)w, o0, o1;
    tf2x32(0u, j, o0, o1);
    unsigned bits = o0 ^ o1;
    float u = __uint_as_float(0x3F800000u | (bits >> 9)) - 1.f;
    float thr = 1.f - p[w];
    bool choice = u < thr;
    need = need || (fabsf(u - thr) < P_MARGIN);
    ch[w] = choice ? 0.f : 1.f;
    prod *= choice ? thr : p[w];
  }
  if (need) {
    unsigned i = atomicAdd(&fixlist[0], 1u);
    if (i < fixcap) fixlist[1 + i] = (unsigned)b;
  }

  float4* oc = reinterpret_cast<float4*>(out_chosen) + (size_t)b * 2;
  oc[0] = make_float4(ch[0], ch[1], ch[2], ch[3]);
  oc[1] = make_float4(ch[4], ch[5], ch[6], ch[7]);
  out_logp[b] = logf(prod);
}

// ---------------- Pass 2: wave-cooperative fp64 repair (R7 shape) --------
// One 64-lane wave per flagged row; lane n computes output neuron n. ~10
// regs/lane hot state, no spills; measured residual ~15us in R7.
__global__ __launch_bounds__(64, 4)
void wtf_fix_kernel(const float* __restrict__ events,
                    const float* __restrict__ W1, const float* __restrict__ b1,
                    const float* __restrict__ g1, const float* __restrict__ be1,
                    const float* __restrict__ W2, const float* __restrict__ b2,
                    const float* __restrict__ g2, const float* __restrict__ be2,
                    const float* __restrict__ W3, const float* __restrict__ b3,
                    const float* __restrict__ g3, const float* __restrict__ be3,
                    const float* __restrict__ W4, const float* __restrict__ b4,
                    const float* __restrict__ W5, const float* __restrict__ b5,
                    float* __restrict__ out_chosen,
                    float* __restrict__ out_logp,
                    const unsigned* __restrict__ fixlist,
                    unsigned fixcap,
                    int B) {
  const unsigned raw = fixlist[0];
  const unsigned cnt = raw < fixcap ? raw : fixcap;
  if (blockIdx.x >= cnt) return;

  __shared__ double sA[64];
  __shared__ double sB[64];
  __shared__ double sF[8];

  const int t = threadIdx.x;
  const double denom = sqrt(1.0 + 1e-5);

  for (unsigned idx = blockIdx.x; idx < cnt; idx += gridDim.x) {
    const int b = (int)fixlist[1 + idx];

    if (t < 32) sA[t] = (double)events[(size_t)b * 32 + t];
    __syncthreads();

    double v = 0.0;
    if (t < 50) {
#pragma unroll
      for (int k = 0; k < 32; ++k) v = fma(sA[k], (double)W1[k * 50 + t], v);
      v += (double)b1[t];
      v = v * ((double)g1[t] / denom) + (double)be1[t];
      v = v > 0.0 ? v : 0.0;
    }
    __syncthreads();
    if (t < 50) sB[t] = v;
    __syncthreads();

    v = 0.0;
    if (t < 30) {
#pragma unroll
      for (int k = 0; k < 50; ++k) v = fma(sB[k], (double)W2[k * 30 + t], v);
      v += (double)b2[t];
      v = v * ((double)g2[t] / denom) + (double)be2[t];
      v = v > 0.0 ? v : 0.0;
    }
    __syncthreads();
    if (t < 30) sA[t] = v;
    __syncthreads();

    v = 0.0;
    if (t < 20) {
#pragma unroll
      for (int k = 0; k < 30; ++k) v = fma(sA[k], (double)W3[k * 20 + t], v);
      v += (double)b3[t];
      v = v * ((double)g3[t] / denom) + (double)be3[t];
      v = v > 0.0 ? v : 0.0;
    }
    __syncthreads();
    if (t < 20) sB[t] = v;
    __syncthreads();

    v = 0.0;
    if (t < 15) {
#pragma unroll
      for (int k = 0; k < 20; ++k) v = fma(sB[k], (double)W4[k * 15 + t], v);
      v += (double)b4[t];
      v = v > 0.0 ? v : 0.0;
    }
    __syncthreads();
    if (t < 15) sA[t] = v;
    __syncthreads();

    if (t < 8) {
      v = 0.0;
#pragma unroll
      for (int k = 0; k < 15; ++k) v = fma(sA[k], (double)W5[k * 8 + t], v);
      v += (double)b5[t];
      double p = 1.0 / (1.0 + exp(-v));
      unsigned j = 8u * (unsigned)b + (unsigned)t, o0, o1;
      tf2x32(0u, j, o0, o1);
      unsigned bits = o0 ^ o1;
      float u = __uint_as_float(0x3F800000u | (bits >> 9)) - 1.f;
      double thr = 1.0 - p;
      bool choice = ((double)u < thr);
      out_chosen[(size_t)b * 8 + t] = choice ? 0.f : 1.f;
      sF[t] = choice ? thr : p;
    }
    __syncthreads();
    if (t == 0) {
      double prod = 1.0;
      for (int w = 0; w < 8; ++w) prod *= sF[w];
      out_logp[b] = (float)log(prod);
    }
    __syncthreads();
  }
}

extern "C" void kernel_launch(void* const* d_in, const int* in_sizes, int n_in,
                              void* d_out, int out_size, void* d_ws, size_t ws_size,
                              hipStream_t stream) {
  const float* events = (const float*)d_in[0];
  const float* W1  = (const float*)d_in[1];
  const float* b1  = (const float*)d_in[2];
  const float* g1  = (const float*)d_in[3];
  const float* be1 = (const float*)d_in[4];
  const float* W2  = (const float*)d_in[5];
  const float* b2  = (const float*)d_in[6];
  const float* g2  = (const float*)d_in[7];
  const float* be2 = (const float*)d_in[8];
  const float* W3  = (const float*)d_in[9];
  const float* b3  = (const float*)d_in[10];
  const float* g3  = (const float*)d_in[11];
  const float* be3 = (const float*)d_in[12];
  const float* W4  = (const float*)d_in[13];
  const float* b4  = (const float*)d_in[14];
  const float* W5  = (const float*)d_in[15];
  const float* b5  = (const float*)d_in[16];

  const int B = in_sizes[0] / 32;  // 524288
  float* out = (float*)d_out;
  float* out_chosen = out;                   // (B, 8)
  float* out_logp   = out + (size_t)B * 8;   // (B,)
  unsigned* fixlist = (unsigned*)d_ws;       // [0]=count, rows at [1+i]
  unsigned fixcap = (unsigned)(ws_size / sizeof(unsigned) - 1);
  if (fixcap > (unsigned)B) fixcap = (unsigned)B;

  hipMemsetAsync(d_ws, 0, sizeof(unsigned), stream);  // zero the counter

  const int blocks = (B + THREADS - 1) / THREADS;
  hipLaunchKernelGGL(wtf_fast_kernel, dim3(blocks), dim3(THREADS), 0, stream,
                     events, W1, b1, g1, be1, W2, b2, g2, be2,
                     W3, b3, g3, be3, W4, b4, W5, b5,
                     out_chosen, out_logp, fixlist, fixcap, B);
  hipLaunchKernelGGL(wtf_fix_kernel, dim3(1024), dim3(64), 0, stream,
                     events, W1, b1, g1, be1, W2, b2, g2, be2,
                     W3, b3, g3, be3, W4, b4, W5, b5,
                     out_chosen, out_logp, fixlist, fixcap, B);
}

// Round 9
// 234.227 us; speedup vs baseline: 13.8824x; 1.0158x over previous
//
#include <hip/hip_runtime.h>
#include <math.h>

#define THREADS 256
// fp32-vs-fp64 p error is <~3e-6 worst case; 1e-4 margin is ~30x safety.
#define P_MARGIN 1e-4f
#define FIXCAP 32

typedef float v2f __attribute__((ext_vector_type(2)));

// Exact JAX threefry2x32 (20 rounds, key schedule every 4), key = (0, 42).
// Partitionable stream: bits[j] = o0 ^ o1 of threefry2x32(key, 0, j).
__device__ __forceinline__ void tf2x32(unsigned x0, unsigned x1,
                                       unsigned &o0, unsigned &o1) {
  const unsigned k0 = 0u;
  const unsigned k1 = 42u;
  const unsigned k2 = 0x1BD11BDAu ^ k0 ^ k1;
  x0 += k0; x1 += k1;
#define TF_R(r) { x0 += x1; x1 = (x1 << (r)) | (x1 >> (32 - (r))); x1 ^= x0; }
  TF_R(13) TF_R(15) TF_R(26) TF_R(6)
  x0 += k1; x1 += k2 + 1u;
  TF_R(17) TF_R(29) TF_R(16) TF_R(24)
  x0 += k2; x1 += k0 + 2u;
  TF_R(13) TF_R(15) TF_R(26) TF_R(6)
  x0 += k0; x1 += k1 + 3u;
  TF_R(17) TF_R(29) TF_R(16) TF_R(24)
  x0 += k1; x1 += k2 + 4u;
  TF_R(13) TF_R(15) TF_R(26) TF_R(6)
  x0 += k2; x1 += k0 + 5u;
#undef TF_R
  o0 = x0; o1 = x1;
}

// Single fused kernel:
//  - fp32 fast path, scalar-cache weights (R8 shape: uniform addresses ->
//    s_load, one fetch per wave), FMA loops packed as float2 so the backend
//    emits v_pk_fma_f32 (VOP3P, full-rate packed fp32): ~2070 packed issues
//    vs 4120 scalar. Bit-identical numerics (same IEEE fp32 FMAs, same order).
//  - rows whose bernoulli comparison is within P_MARGIN of the threshold go
//    to a per-block LDS list; after a barrier the block cooperatively re-runs
//    them in fp64 (lane=neuron, R7's validated repair shape) and overwrites.
//    Expected ~0.4 flagged rows/block; cap 32 (P(overflow) ~ 1e-40).
__global__ __launch_bounds__(THREADS, 4)
void wtf_kernel(const float* __restrict__ events,
                const float* __restrict__ W1, const float* __restrict__ b1,
                const float* __restrict__ g1, const float* __restrict__ be1,
                const float* __restrict__ W2, const float* __restrict__ b2,
                const float* __restrict__ g2, const float* __restrict__ be2,
                const float* __restrict__ W3, const float* __restrict__ b3,
                const float* __restrict__ g3, const float* __restrict__ be3,
                const float* __restrict__ W4, const float* __restrict__ b4,
                const float* __restrict__ W5, const float* __restrict__ b5,
                float* __restrict__ out_chosen,
                float* __restrict__ out_logp,
                int B) {
  __shared__ unsigned s_cnt;
  __shared__ unsigned s_rows[FIXCAP];
  __shared__ double sA[64];
  __shared__ double sB[64];
  __shared__ double sF[8];

  const int t = threadIdx.x;
  if (t == 0) s_cnt = 0;
  __syncthreads();

  const int b = blockIdx.x * THREADS + t;
  const bool active = (b < B);
  const float rden = (float)(1.0 / sqrt(1.0 + 1e-5));

  if (active) {
    float x[32];
    const float4* ev4 = reinterpret_cast<const float4*>(events) + (size_t)b * 8;
#pragma unroll
    for (int q = 0; q < 8; ++q) {
      float4 v = ev4[q];
      x[4 * q + 0] = v.x; x[4 * q + 1] = v.y; x[4 * q + 2] = v.z; x[4 * q + 3] = v.w;
    }

    // ---- layer 1: 32 -> 50, BN + ReLU (packed f32x2 accumulators) ----
    v2f A[25];
#pragma unroll
    for (int j = 0; j < 25; ++j) A[j] = v2f{b1[2 * j], b1[2 * j + 1]};
#pragma unroll
    for (int k = 0; k < 32; ++k) {
      const v2f xk2 = {x[k], x[k]};
#pragma unroll
      for (int j = 0; j < 25; ++j) {
        v2f w = {W1[k * 50 + 2 * j], W1[k * 50 + 2 * j + 1]};
        A[j] = __builtin_elementwise_fma(xk2, w, A[j]);
      }
    }
    float a1[50];
#pragma unroll
    for (int j = 0; j < 25; ++j) {
      a1[2 * j + 0] = fmaxf(fmaf(A[j].x, g1[2 * j + 0] * rden, be1[2 * j + 0]), 0.f);
      a1[2 * j + 1] = fmaxf(fmaf(A[j].y, g1[2 * j + 1] * rden, be1[2 * j + 1]), 0.f);
    }

    // ---- layer 2: 50 -> 30, BN + ReLU ----
    v2f C[15];
#pragma unroll
    for (int j = 0; j < 15; ++j) C[j] = v2f{b2[2 * j], b2[2 * j + 1]};
#pragma unroll
    for (int k = 0; k < 50; ++k) {
      const v2f hk2 = {a1[k], a1[k]};
#pragma unroll
      for (int j = 0; j < 15; ++j) {
        v2f w = {W2[k * 30 + 2 * j], W2[k * 30 + 2 * j + 1]};
        C[j] = __builtin_elementwise_fma(hk2, w, C[j]);
      }
    }
    float a2[30];
#pragma unroll
    for (int j = 0; j < 15; ++j) {
      a2[2 * j + 0] = fmaxf(fmaf(C[j].x, g2[2 * j + 0] * rden, be2[2 * j + 0]), 0.f);
      a2[2 * j + 1] = fmaxf(fmaf(C[j].y, g2[2 * j + 1] * rden, be2[2 * j + 1]), 0.f);
    }

    // ---- layer 3: 30 -> 20, BN + ReLU ----
    v2f D[10];
#pragma unroll
    for (int j = 0; j < 10; ++j) D[j] = v2f{b3[2 * j], b3[2 * j + 1]};
#pragma unroll
    for (int k = 0; k < 30; ++k) {
      const v2f hk2 = {a2[k], a2[k]};
#pragma unroll
      for (int j = 0; j < 10; ++j) {
        v2f w = {W3[k * 20 + 2 * j], W3[k * 20 + 2 * j + 1]};
        D[j] = __builtin_elementwise_fma(hk2, w, D[j]);
      }
    }
    float a3[20];
#pragma unroll
    for (int j = 0; j < 10; ++j) {
      a3[2 * j + 0] = fmaxf(fmaf(D[j].x, g3[2 * j + 0] * rden, be3[2 * j + 0]), 0.f);
      a3[2 * j + 1] = fmaxf(fmaf(D[j].y, g3[2 * j + 1] * rden, be3[2 * j + 1]), 0.f);
    }

    // ---- layer 4: 20 -> 15, ReLU (no BN); 7 pairs + 1 scalar tail ----
    v2f E[7];
    float e14 = b4[14];
#pragma unroll
    for (int j = 0; j < 7; ++j) E[j] = v2f{b4[2 * j], b4[2 * j + 1]};
#pragma unroll
    for (int k = 0; k < 20; ++k) {
      const float hk = a3[k];
      const v2f hk2 = {hk, hk};
#pragma unroll
      for (int j = 0; j < 7; ++j) {
        v2f w = {W4[k * 15 + 2 * j], W4[k * 15 + 2 * j + 1]};
        E[j] = __builtin_elementwise_fma(hk2, w, E[j]);
      }
      e14 = fmaf(hk, W4[k * 15 + 14], e14);
    }
    float a4[15];
#pragma unroll
    for (int j = 0; j < 7; ++j) {
      a4[2 * j + 0] = fmaxf(E[j].x, 0.f);
      a4[2 * j + 1] = fmaxf(E[j].y, 0.f);
    }
    a4[14] = fmaxf(e14, 0.f);

    // ---- layer 5: 15 -> 8, sigmoid ----
    v2f P[4];
#pragma unroll
    for (int j = 0; j < 4; ++j) P[j] = v2f{b5[2 * j], b5[2 * j + 1]};
#pragma unroll
    for (int k = 0; k < 15; ++k) {
      const v2f hk2 = {a4[k], a4[k]};
#pragma unroll
      for (int j = 0; j < 4; ++j) {
        v2f w = {W5[k * 8 + 2 * j], W5[k * 8 + 2 * j + 1]};
        P[j] = __builtin_elementwise_fma(hk2, w, P[j]);
      }
    }
    float p[8];
#pragma unroll
    for (int j = 0; j < 4; ++j) {
      p[2 * j + 0] = 1.f / (1.f + expf(-P[j].x));
      p[2 * j + 1] = 1.f / (1.f + expf(-P[j].y));
    }

    // ---- bernoulli(1-p) via partitionable threefry + margin flag ----
    bool need = false;
    float prod = 1.f;
    float ch[8];
#pragma unroll
    for (int w = 0; w < 8; ++w) {
      unsigned j = 8u * (unsigned)b + (unsigned)w, o0, o1;
      tf2x32(0u, j, o0, o1);
      unsigned bits = o0 ^ o1;
      float u = __uint_as_float(0x3F800000u | (bits >> 9)) - 1.f;
      float thr = 1.f - p[w];
      bool choice = u < thr;
      need = need || (fabsf(u - thr) < P_MARGIN);
      ch[w] = choice ? 0.f : 1.f;
      prod *= choice ? thr : p[w];
    }
    if (need) {
      unsigned i = atomicAdd(&s_cnt, 1u);
      if (i < FIXCAP) s_rows[i] = (unsigned)b;
    }

    float4* oc = reinterpret_cast<float4*>(out_chosen) + (size_t)b * 2;
    oc[0] = make_float4(ch[0], ch[1], ch[2], ch[3]);
    oc[1] = make_float4(ch[4], ch[5], ch[6], ch[7]);
    out_logp[b] = logf(prod);
  }

  // ---- block-cooperative fp64 repair of flagged rows (overwrites) ----
  __syncthreads();  // also drains this block's fp32 stores (vmcnt at barrier)
  unsigned cnt = s_cnt;
  if (cnt > FIXCAP) cnt = FIXCAP;
  if (cnt == 0) return;

  const double denom = sqrt(1.0 + 1e-5);
  for (unsigned r = 0; r < cnt; ++r) {  // cnt is block-uniform
    const int rb = (int)s_rows[r];

    if (t < 32) sA[t] = (double)events[(size_t)rb * 32 + t];
    __syncthreads();

    double v = 0.0;
    if (t < 50) {
#pragma unroll
      for (int k = 0; k < 32; ++k) v = fma(sA[k], (double)W1[k * 50 + t], v);
      v += (double)b1[t];
      v = v * ((double)g1[t] / denom) + (double)be1[t];
      v = v > 0.0 ? v : 0.0;
    }
    __syncthreads();
    if (t < 50) sB[t] = v;
    __syncthreads();

    v = 0.0;
    if (t < 30) {
#pragma unroll
      for (int k = 0; k < 50; ++k) v = fma(sB[k], (double)W2[k * 30 + t], v);
      v += (double)b2[t];
      v = v * ((double)g2[t] / denom) + (double)be2[t];
      v = v > 0.0 ? v : 0.0;
    }
    __syncthreads();
    if (t < 30) sA[t] = v;
    __syncthreads();

    v = 0.0;
    if (t < 20) {
#pragma unroll
      for (int k = 0; k < 30; ++k) v = fma(sA[k], (double)W3[k * 20 + t], v);
      v += (double)b3[t];
      v = v * ((double)g3[t] / denom) + (double)be3[t];
      v = v > 0.0 ? v : 0.0;
    }
    __syncthreads();
    if (t < 20) sB[t] = v;
    __syncthreads();

    v = 0.0;
    if (t < 15) {
#pragma unroll
      for (int k = 0; k < 20; ++k) v = fma(sB[k], (double)W4[k * 15 + t], v);
      v += (double)b4[t];
      v = v > 0.0 ? v : 0.0;
    }
    __syncthreads();
    if (t < 15) sA[t] = v;
    __syncthreads();

    if (t < 8) {
      v = 0.0;
#pragma unroll
      for (int k = 0; k < 15; ++k) v = fma(sA[k], (double)W5[k * 8 + t], v);
      v += (double)b5[t];
      double p = 1.0 / (1.0 + exp(-v));
      unsigned j = 8u * (unsigned)rb + (unsigned)t, o0, o1;
      tf2x32(0u, j, o0, o1);
      unsigned bits = o0 ^ o1;
      float u = __uint_as_float(0x3F800000u | (bits >> 9)) - 1.f;
      double thr = 1.0 - p;
      bool choice = ((double)u < thr);
      out_chosen[(size_t)rb * 8 + t] = choice ? 0.f : 1.f;
      sF[t] = choice ? thr : p;
    }
    __syncthreads();
    if (t == 0) {
      double prod = 1.0;
      for (int w = 0; w < 8; ++w) prod *= sF[w];
      out_logp[rb] = (float)log(prod);
    }
    __syncthreads();
  }
}

extern "C" void kernel_launch(void* const* d_in, const int* in_sizes, int n_in,
                              void* d_out, int out_size, void* d_ws, size_t ws_size,
                              hipStream_t stream) {
  const float* events = (const float*)d_in[0];
  const float* W1  = (const float*)d_in[1];
  const float* b1  = (const float*)d_in[2];
  const float* g1  = (const float*)d_in[3];
  const float* be1 = (const float*)d_in[4];
  const float* W2  = (const float*)d_in[5];
  const float* b2  = (const float*)d_in[6];
  const float* g2  = (const float*)d_in[7];
  const float* be2 = (const float*)d_in[8];
  const float* W3  = (const float*)d_in[9];
  const float* b3  = (const float*)d_in[10];
  const float* g3  = (const float*)d_in[11];
  const float* be3 = (const float*)d_in[12];
  const float* W4  = (const float*)d_in[13];
  const float* b4  = (const float*)d_in[14];
  const float* W5  = (const float*)d_in[15];
  const float* b5  = (const float*)d_in[16];

  const int B = in_sizes[0] / 32;  // 524288
  float* out = (float*)d_out;
  float* out_chosen = out;                   // (B, 8)
  float* out_logp   = out + (size_t)B * 8;   // (B,)

  const int blocks = (B + THREADS - 1) / THREADS;
  hipLaunchKernelGGL(wtf_kernel, dim3(blocks), dim3(THREADS), 0, stream,
                     events, W1, b1, g1, be1, W2, b2, g2, be2,
                     W3, b3, g3, be3, W4, b4, W5, b5,
                     out_chosen, out_logp, B);
}